// Round 6
// baseline (238.145 us; speedup 1.0000x reference)
//
#include <hip/hip_runtime.h>

// BEiT self-attention: B=64, S=197, D=768, H=12, HD=64
// Pipeline:
//   1. k_prep      : fused grid-stride prep — hidden fp32->bf16 (pad rows zero),
//                    W combine fp32->bf16 [2304][768], bias -> MFMA-C-frag layout
//   2. k_gemm_qkv  : MFMA GEMM, BK=64 (12 barrier-pairs, 32 MFMA/window), global_load_lds
//                    staging w/ 3-bit XOR swizzle; XCD-aware tile remap; Q pre-scaled 0.125
//   3. k_attn_mfma : transposed attention S^T=K*Q^T, O^T=V^T*P^T; K a-frags + V^T in LDS;
//                    P via quad-shfl; O transposed through per-wave LDS -> coalesced stores

#define S_LEN 197
#define HEADS 12
#define HDIM 64
#define DMODEL 768
#define BATCH 64
#define MROWS (BATCH * S_LEN) /* 12608 */
#define MPAD 12672
#define NCOLS (3 * DMODEL) /* 2304 */
#define KDIM 768
#define NQT 13 /* ceil(197/16) */
#define NTILE (NCOLS / 128) /* 18 */
#define MTILE (MPAD / 128)  /* 99 */
#define OS_ST 76 /* dwords per Os row (16B-aligned, bank-clean) */

typedef __attribute__((ext_vector_type(8))) short short8;
typedef __attribute__((ext_vector_type(4))) float floatx4;

#define GLD16(gp, lp)                                                                  \
  __builtin_amdgcn_global_load_lds(                                                    \
      (const __attribute__((address_space(1))) unsigned int*)(gp),                     \
      (__attribute__((address_space(3))) unsigned int*)(lp), 16, 0, 0)

__device__ __forceinline__ ushort f2bf(float f) {
  union { float f; unsigned int i; } x;
  x.f = f;
  unsigned int r = x.i + 0x7fffu + ((x.i >> 16) & 1u); // RNE
  return (ushort)(r >> 16);
}

// fused prep: one launch, grid-stride over three independent sections
__global__ __launch_bounds__(256) void k_prep(
    const float* __restrict__ hs, const float* __restrict__ wq,
    const float* __restrict__ wk, const float* __restrict__ wv,
    const float* __restrict__ bt, const int* __restrict__ ridx,
    ushort* __restrict__ hbf, ushort* __restrict__ wbf, float* __restrict__ biasF) {
  int gid = blockIdx.x * 256 + threadIdx.x;
  int gsz = gridDim.x * 256;
  for (int i = gid; i < MPAD * KDIM / 8; i += gsz) {
    int base = i * 8;
    int row = base / KDIM;
    ushort o[8];
    if (row < MROWS) {
      const float* s = hs + (size_t)base;
#pragma unroll
      for (int e = 0; e < 8; ++e) o[e] = f2bf(s[e]);
    } else {
#pragma unroll
      for (int e = 0; e < 8; ++e) o[e] = 0;
    }
    *(uint4*)&hbf[base] = *(const uint4*)o;
  }
  for (int i = gid; i < NCOLS * KDIM / 8; i += gsz) {
    int base = i * 8;
    int row = base / KDIM;
    int col = base - row * KDIM;
    const float* src = (row < DMODEL) ? &wq[(size_t)row * KDIM]
                       : (row < 2 * DMODEL) ? &wk[(size_t)(row - DMODEL) * KDIM]
                                            : &wv[(size_t)(row - 2 * DMODEL) * KDIM];
    ushort o[8];
#pragma unroll
    for (int e = 0; e < 8; ++e) o[e] = f2bf(src[col + e]);
    *(uint4*)&wbf[base] = *(const uint4*)o;
  }
  // biasF[h][qt][t][lane][r]: C-frag of S^T tile (row=key=quad*4+r, col=q=l16); mask baked
  for (int idx = gid; idx < HEADS * NQT * NQT * 64; idx += gsz) {
    int lane = idx & 63;
    int rest = idx >> 6;
    int t = rest % NQT;
    int rest2 = rest / NQT;
    int qt = rest2 % NQT;
    int h = rest2 / NQT;
    int l16 = lane & 15, quad = lane >> 4;
    int q = qt * 16 + l16;
    floatx4 v;
#pragma unroll
    for (int r = 0; r < 4; ++r) {
      int key = t * 16 + quad * 4 + r;
      float x = -1e30f;
      if (q < S_LEN && key < S_LEN) x = bt[ridx[q * S_LEN + key] * HEADS + h];
      v[r] = x;
    }
    *(floatx4*)&biasF[(size_t)idx * 4] = v;
  }
}

// 128x128 tile, BK=64: 12 barrier-pairs, 32 MFMA per window. Staging position p
// (row=p>>3, c=p&7) holds global chunk c^(row&7); fragment read chunk
// (kk*4+quad)^(l16&7) -> each 8-lane phase covers all 8 bank groups (row stride
// 32 dwords == 0 mod 32, so the 3-bit XOR carries all decorrelation).
__global__ __launch_bounds__(256) void k_gemm_qkv(
    const ushort* __restrict__ A, const ushort* __restrict__ W,
    const float* __restrict__ bq, const float* __restrict__ bv,
    ushort* __restrict__ Cb) {
  __shared__ __align__(16) ushort SH[128 * 128]; // staging (2x16KB) U epilogue tile (32KB)
  ushort* As = SH;
  ushort* Bs = SH + 128 * 64;
  int tid = threadIdx.x;
  int wave = tid >> 6, lane = tid & 63;
  int quad = lane >> 4, l16 = lane & 15;

  // XCD-aware remap: each XCD gets a contiguous run of m-bands
  int linear = blockIdx.y * NTILE + blockIdx.x;
  int m_t, n_t;
  if (linear < 1776) { // 8 * 222
    int g = (linear & 7) * 222 + (linear >> 3);
    m_t = g / NTILE;
    n_t = g - m_t * NTILE;
  } else {
    m_t = linear / NTILE;
    n_t = linear - m_t * NTILE;
  }
  int m0 = m_t * 128, n0 = n_t * 128;
  int wm = (wave & 1) * 64, wn = (wave >> 1) * 64;

  floatx4 acc[4][4];
  floatx4 z = {0.f, 0.f, 0.f, 0.f};
#pragma unroll
  for (int i = 0; i < 4; ++i)
#pragma unroll
    for (int j = 0; j < 4; ++j) acc[i][j] = z;

  for (int kb = 0; kb < KDIM; kb += 64) {
    const ushort* Arow = A + (size_t)m0 * KDIM + kb;
    const ushort* Brow = W + (size_t)n0 * KDIM + kb;
#pragma unroll
    for (int s = 0; s < 4; ++s) {
      int p = s * 256 + tid; // 0..1023
      int r = p >> 3;
      int kc = (((p & 7) ^ (r & 7))) << 3;
      GLD16(&Arow[(size_t)r * KDIM + kc], &As[p * 8]);
      GLD16(&Brow[(size_t)r * KDIM + kc], &Bs[p * 8]);
    }
    __syncthreads();
#pragma unroll
    for (int kk = 0; kk < 2; ++kk) {
      int coff = ((kk * 4 + quad) ^ (l16 & 7)) << 3;
      short8 af[4], bfr[4];
#pragma unroll
      for (int i = 0; i < 4; ++i) {
        af[i] = *(const short8*)(&As[(wm + i * 16 + l16) * 64 + coff]);
        bfr[i] = *(const short8*)(&Bs[(wn + i * 16 + l16) * 64 + coff]);
      }
#pragma unroll
      for (int i = 0; i < 4; ++i)
#pragma unroll
        for (int j = 0; j < 4; ++j)
          acc[i][j] = __builtin_amdgcn_mfma_f32_16x16x32_bf16(af[i], bfr[j], acc[i][j], 0, 0, 0);
    }
    __syncthreads(); // also guards SH reuse in epilogue on last iteration
  }

  // epilogue: acc (+bias, q-scale) -> swizzled bf16 tile in SH -> full-line dwordx4 stores
#pragma unroll
  for (int j = 0; j < 4; ++j) {
    int coln = wn + j * 16 + l16;
    int col = n0 + coln;
    float bias = (col < DMODEL) ? bq[col] : ((col >= 2 * DMODEL) ? bv[col - 2 * DMODEL] : 0.f);
    float scl = (col < DMODEL) ? 0.125f : 1.0f;
#pragma unroll
    for (int i = 0; i < 4; ++i)
#pragma unroll
      for (int r = 0; r < 4; ++r) {
        int row = wm + i * 16 + quad * 4 + r;
        int ch = (coln >> 3) ^ (row & 7);
        SH[row * 128 + (ch << 3) + (coln & 7)] = f2bf((acc[i][j][r] + bias) * scl);
      }
  }
  __syncthreads();
#pragma unroll
  for (int p = 0; p < 2; ++p) {
    int row = p * 64 + wave * 16 + (lane >> 2);
    int q4 = lane & 3;
    ushort* gC = Cb + (size_t)(m0 + row) * NCOLS + n0;
#pragma unroll
    for (int c = 0; c < 4; ++c) {
      int cp = c * 4 + q4;
      int ch = cp ^ (row & 7);
      *(uint4*)&gC[cp * 8] = *(const uint4*)&SH[row * 128 + (ch << 3)];
    }
  }
}

// Transposed MFMA attention. One block per (b,h), 4 independent waves (qt = wave+4k).
// K a-frags + V^T staged in LDS; S^T = K*Q^T; softmax per column (2 shfls);
// P -> PV B-frag via quad-shfl; O^T transposed through per-wave LDS scratch so
// global stores are 4x coalesced float4 rows (256B per 16 lanes).
__global__ __launch_bounds__(256) void k_attn_mfma(
    const ushort* __restrict__ Cb0, const float* __restrict__ biasF,
    float* __restrict__ out) {
  __shared__ __align__(16) ushort Vt[HDIM * 256];      // 32768 B, [d][key] swizzled
  __shared__ __align__(16) ushort Ka[NQT * 2 * 512];   // 26624 B, [t][half][lane][8]
  __shared__ __align__(16) float Os[4 * 16 * OS_ST];   // 19456 B, per-wave O transpose
  int bh = blockIdx.x;
  int b = bh / HEADS, h = bh - b * HEADS;
  int tid = threadIdx.x;
  int wave = tid >> 6, lane = tid & 63;
  int quad = lane >> 4, l16 = lane & 15;
  const ushort* Cb = Cb0 + (size_t)b * S_LEN * NCOLS;
  const int qoff = h * HDIM, koff = DMODEL + h * HDIM, voff = 2 * DMODEL + h * HDIM;

  { // zero Vt (key cols 197..255 must be 0.0)
    uint4 z4 = {0u, 0u, 0u, 0u};
    for (int i = tid; i < HDIM * 256 / 8; i += 256) ((uint4*)Vt)[i] = z4;
  }
  __syncthreads();
  for (int idx = tid; idx < S_LEN * 32; idx += 256) { // V -> V^T (swizzled scatter)
    int key = idx >> 5, dp = (idx & 31) * 2;
    unsigned int v = *(const unsigned int*)&Cb[(size_t)key * NCOLS + voff + dp];
    int ch = key >> 3, co = key & 7;
    Vt[dp * 256 + ((ch ^ (dp & 7)) << 3) + co] = (ushort)(v & 0xffffu);
    Vt[(dp + 1) * 256 + ((ch ^ ((dp + 1) & 7)) << 3) + co] = (ushort)(v >> 16);
  }
  // stage K a-frags: rows up to 207 read neighbor-batch data (finite; masked by bias)
  for (int th = wave; th < NQT * 2; th += 4) {
    int t = th >> 1, half = th & 1;
    short8 kf = *(const short8*)&Cb[(size_t)(t * 16 + l16) * NCOLS + koff + half * 32 + quad * 8];
    *(short8*)&Ka[th * 512 + lane * 8] = kf;
  }
  __syncthreads(); // last barrier; waves independent below

  float* Osw = Os + wave * 16 * OS_ST;
  for (int qt = wave; qt < NQT; qt += 4) {
    int q0 = qt * 16;
    int q = q0 + l16;
    short8 qb0 = *(const short8*)&Cb[(size_t)q * NCOLS + qoff + quad * 8];
    short8 qb1 = *(const short8*)&Cb[(size_t)q * NCOLS + qoff + 32 + quad * 8];
    const float* bF = biasF + ((size_t)((h * NQT + qt) * NQT) * 64 + lane) * 4;

    floatx4 sacc[NQT];
#pragma unroll
    for (int t = 0; t < NQT; ++t) {
      floatx4 cin = *(const floatx4*)&bF[t * 256]; // bias as MFMA C-init (mask baked in)
      short8 ka0 = *(const short8*)&Ka[(t * 2 + 0) * 512 + lane * 8];
      short8 ka1 = *(const short8*)&Ka[(t * 2 + 1) * 512 + lane * 8];
      floatx4 s1 = __builtin_amdgcn_mfma_f32_16x16x32_bf16(ka0, qb0, cin, 0, 0, 0);
      sacc[t] = __builtin_amdgcn_mfma_f32_16x16x32_bf16(ka1, qb1, s1, 0, 0, 0);
    }

    // softmax over keys (spread across quads+regs+tiles at fixed col q)
    float mx = -3e38f;
#pragma unroll
    for (int t = 0; t < NQT; ++t)
#pragma unroll
      for (int r = 0; r < 4; ++r) mx = fmaxf(mx, sacc[t][r]);
    mx = fmaxf(mx, __shfl_xor(mx, 16));
    mx = fmaxf(mx, __shfl_xor(mx, 32));
    float sum = 0.f;
    unsigned int pbf[NQT][2]; // packed bf16 pairs (rows 2r,2r+1), unnormalized
#pragma unroll
    for (int t = 0; t < NQT; ++t) {
      float e0 = __expf(sacc[t][0] - mx), e1 = __expf(sacc[t][1] - mx);
      float e2 = __expf(sacc[t][2] - mx), e3 = __expf(sacc[t][3] - mx);
      sum += (e0 + e1) + (e2 + e3);
      union { float f; unsigned int u; } a, bb, c, d;
      a.f = e0; bb.f = e1; c.f = e2; d.f = e3;
      pbf[t][0] = ((a.u + 0x8000u) >> 16) | ((bb.u + 0x8000u) & 0xffff0000u);
      pbf[t][1] = ((c.u + 0x8000u) >> 16) | ((d.u + 0x8000u) & 0xffff0000u);
    }
    sum += __shfl_xor(sum, 16);
    sum += __shfl_xor(sum, 32);
    float inv = 1.f / sum;

    // PV: O^T[d][q]; B-frag(P) lane(quad,l16) needs keys kk*32+quad*8+j of col q=l16
    floatx4 oacc[4];
    floatx4 zz = {0.f, 0.f, 0.f, 0.f};
#pragma unroll
    for (int dt = 0; dt < 4; ++dt) oacc[dt] = zz;
    int sel0 = ((quad & 1) * 2) * 16 + l16;
    int sel1 = sel0 + 16;
#pragma unroll
    for (int kk = 0; kk < 7; ++kk) {
      unsigned int u0 = 0, u1 = 0, u2 = 0, u3 = 0;
#pragma unroll
      for (int half = 0; half < 2; ++half) {
        int t = 2 * kk + half;
        if (t < NQT) {
          unsigned int v0 = __shfl((int)pbf[t][0], sel0);
          unsigned int v1 = __shfl((int)pbf[t][1], sel0);
          unsigned int v2 = __shfl((int)pbf[t][0], sel1);
          unsigned int v3 = __shfl((int)pbf[t][1], sel1);
          if ((quad >> 1) == half) { u0 = v0; u1 = v1; u2 = v2; u3 = v3; }
        }
      }
      union { uint4 u; short8 s; } pf;
      pf.u.x = u0; pf.u.y = u1; pf.u.z = u2; pf.u.w = u3;
#pragma unroll
      for (int dt = 0; dt < 4; ++dt) {
        int d = dt * 16 + l16;
        short8 vf = *(const short8*)&Vt[d * 256 + (((kk * 4 + quad) ^ (d & 7)) << 3)];
        oacc[dt] = __builtin_amdgcn_mfma_f32_16x16x32_bf16(vf, pf.s, oacc[dt], 0, 0, 0);
      }
    }

    // O^T C-layout: row=d=dt*16+quad*4+r, col=q=l16. Normalize, transpose via
    // wave-private LDS (no barrier; compiler inserts lgkmcnt), store coalesced.
#pragma unroll
    for (int dt = 0; dt < 4; ++dt) {
      floatx4 o;
#pragma unroll
      for (int r = 0; r < 4; ++r) o[r] = oacc[dt][r] * inv;
      *(floatx4*)&Osw[l16 * OS_ST + dt * 16 + quad * 4] = o;
    }
    float* outg = out + ((size_t)b * S_LEN) * DMODEL + h * HDIM;
#pragma unroll
    for (int i = 0; i < 4; ++i) {
      int ql = i * 4 + (lane >> 4);
      float4 o4 = *(const float4*)&Osw[ql * OS_ST + (lane & 15) * 4];
      int qg = q0 + ql;
      if (qg < S_LEN) *(float4*)&outg[(size_t)qg * DMODEL + (lane & 15) * 4] = o4;
    }
  }
}

extern "C" void kernel_launch(void* const* d_in, const int* in_sizes, int n_in,
                              void* d_out, int out_size, void* d_ws, size_t ws_size,
                              hipStream_t stream) {
  const float* hs = (const float*)d_in[0];
  const float* wq = (const float*)d_in[1];
  const float* bq = (const float*)d_in[2];
  const float* wk = (const float*)d_in[3];
  const float* wv = (const float*)d_in[4];
  const float* bv = (const float*)d_in[5];
  const float* bt = (const float*)d_in[6];
  const int* ridx = (const int*)d_in[7];
  float* out = (float*)d_out;

  // workspace (~83.5 MB)
  ushort* hbf = (ushort*)d_ws;              // [12672][768] bf16
  ushort* wbf = hbf + (size_t)MPAD * KDIM;  // [2304][768] bf16
  ushort* Cb = wbf + (size_t)NCOLS * KDIM;  // [12672][2304] bf16 (QKV combined)
  float* biasF = (float*)(Cb + (size_t)MPAD * NCOLS); // [12][13][13][64][4] fp32

  k_prep<<<2048, 256, 0, stream>>>(hs, wq, wk, wv, bt, ridx, hbf, wbf, biasF);
  k_gemm_qkv<<<dim3(NTILE, MTILE), 256, 0, stream>>>(hbf, wbf, bq, bv, Cb);
  k_attn_mfma<<<BATCH * HEADS, 256, 0, stream>>>(Cb, biasF, out);
}